// Round 1
// baseline (447.460 us; speedup 1.0000x reference)
//
#include <hip/hip_runtime.h>

#define NN 50000
#define EE 800000
#define ETOT (EE + NN)          // 850000
#define HIDD 64
#define NHEADS 4
#define GDIM 16
#define FCD 160
#define OUTD 64

// ---------------- CSR build ----------------

__global__ void k_count(const int* __restrict__ ei, int* __restrict__ deg) {
    int i = blockIdx.x * 256 + threadIdx.x;
    if (i >= ETOT) return;
    int dst = (i < EE) ? ei[EE + i] : (i - EE);
    atomicAdd(&deg[dst], 1);
}

__global__ __launch_bounds__(1024) void k_scan(const int* __restrict__ deg,
                                               int* __restrict__ rowptr,
                                               int* __restrict__ woff) {
    __shared__ int part[1024];
    int t = threadIdx.x;
    const int CH = (NN + 1023) / 1024;   // 49
    int beg = t * CH, end = min(beg + CH, NN);
    int s = 0;
    for (int i = beg; i < end; i++) s += deg[i];
    part[t] = s;
    __syncthreads();
    for (int off = 1; off < 1024; off <<= 1) {
        int v = (t >= off) ? part[t - off] : 0;
        __syncthreads();
        part[t] += v;
        __syncthreads();
    }
    int run = (t == 0) ? 0 : part[t - 1];
    for (int i = beg; i < end; i++) {
        rowptr[i] = run; woff[i] = run; run += deg[i];
    }
    if (t == 1023) rowptr[NN] = part[1023];
}

__global__ void k_scatter(const int* __restrict__ ei, int* __restrict__ woff,
                          int* __restrict__ csrc) {
    int i = blockIdx.x * 256 + threadIdx.x;
    if (i >= ETOT) return;
    int src, dst;
    if (i < EE) { src = ei[i]; dst = ei[EE + i]; }
    else { src = dst = i - EE; }
    int pos = atomicAdd(&woff[dst], 1);
    csrc[pos] = src;
}

// ---------------- GEMM h = x@W + per-node attention scores ----------------
// block = 256 threads, 16 nodes/block, each thread 4 consecutive outputs.

template<int FIN>
__global__ __launch_bounds__(256) void k_gemm_scores(
        const float* __restrict__ x, const float* __restrict__ W,
        const float* __restrict__ a_src, const float* __restrict__ a_dst,
        float* __restrict__ h, float* __restrict__ ssrc, float* __restrict__ sdst) {
    __shared__ float wlds[FIN * HIDD];
    __shared__ float xlds[16 * FIN];
    int t = threadIdx.x;
    int nb = blockIdx.x * 16;
    for (int i = t; i < FIN * HIDD / 4; i += 256)
        ((float4*)wlds)[i] = ((const float4*)W)[i];
    for (int i = t; i < 16 * FIN / 4; i += 256)
        ((float4*)xlds)[i] = ((const float4*)(x + (size_t)nb * FIN))[i];
    __syncthreads();

    int nl = t >> 4;          // local node 0..15
    int q  = t & 15;          // j-quad 0..15
    int j0 = q * 4;
    float a0 = 0.f, a1 = 0.f, a2 = 0.f, a3 = 0.f;
    const float4* wl4 = (const float4*)wlds;
    const float4* xl4 = (const float4*)(xlds + nl * FIN);
    #pragma unroll
    for (int k4 = 0; k4 < FIN / 4; k4++) {
        float4 xv = xl4[k4];
        float4 wa = wl4[(k4 * 4 + 0) * 16 + q];
        float4 wb = wl4[(k4 * 4 + 1) * 16 + q];
        float4 wc = wl4[(k4 * 4 + 2) * 16 + q];
        float4 wd = wl4[(k4 * 4 + 3) * 16 + q];
        a0 += xv.x * wa.x + xv.y * wb.x + xv.z * wc.x + xv.w * wd.x;
        a1 += xv.x * wa.y + xv.y * wb.y + xv.z * wc.y + xv.w * wd.y;
        a2 += xv.x * wa.z + xv.y * wb.z + xv.z * wc.z + xv.w * wd.z;
        a3 += xv.x * wa.w + xv.y * wb.w + xv.z * wc.w + xv.w * wd.w;
    }
    int n = nb + nl;
    float4 hv = {a0, a1, a2, a3};
    *(float4*)(h + (size_t)n * HIDD + j0) = hv;

    float vs = a0 * a_src[j0] + a1 * a_src[j0 + 1] + a2 * a_src[j0 + 2] + a3 * a_src[j0 + 3];
    float vd = a0 * a_dst[j0] + a1 * a_dst[j0 + 1] + a2 * a_dst[j0 + 2] + a3 * a_dst[j0 + 3];
    vs += __shfl_xor(vs, 1); vs += __shfl_xor(vs, 2);
    vd += __shfl_xor(vd, 1); vd += __shfl_xor(vd, 2);
    if ((q & 3) == 0) {
        ssrc[n * NHEADS + (q >> 2)] = vs;
        sdst[n * NHEADS + (q >> 2)] = vd;
    }
}

// ---------------- per-destination aggregation (1 wave per node) ----------------

__global__ __launch_bounds__(64) void k_aggr(
        const float* __restrict__ h, const float* __restrict__ ssrc,
        const float* __restrict__ sdst, const int* __restrict__ rowptr,
        const int* __restrict__ csrc, const float* __restrict__ bias,
        float* __restrict__ out) {
    __shared__ float exl[64 * 4];
    __shared__ int srcl[64];
    int n = blockIdx.x;
    int lane = threadIdx.x;
    int hd = lane >> 4;
    int beg = rowptr[n], end = rowptr[n + 1];
    float4 sd = ((const float4*)sdst)[n];

    // sweep 1: softmax denominator per head (max-subtraction cancels in alpha; scores are O(1))
    float z0 = 0.f, z1 = 0.f, z2 = 0.f, z3 = 0.f;
    for (int i = beg + lane; i < end; i += 64) {
        int s = csrc[i];
        float4 ss = ((const float4*)ssrc)[s];
        float e0 = ss.x + sd.x; e0 = e0 > 0.f ? e0 : 0.2f * e0; z0 += __expf(e0);
        float e1 = ss.y + sd.y; e1 = e1 > 0.f ? e1 : 0.2f * e1; z1 += __expf(e1);
        float e2 = ss.z + sd.z; e2 = e2 > 0.f ? e2 : 0.2f * e2; z2 += __expf(e2);
        float e3 = ss.w + sd.w; e3 = e3 > 0.f ? e3 : 0.2f * e3; z3 += __expf(e3);
    }
    for (int m = 1; m < 64; m <<= 1) {
        z0 += __shfl_xor(z0, m); z1 += __shfl_xor(z1, m);
        z2 += __shfl_xor(z2, m); z3 += __shfl_xor(z3, m);
    }
    float zh = (hd == 0) ? z0 : (hd == 1) ? z1 : (hd == 2) ? z2 : z3;
    float inv_z = 1.0f / (zh + 1e-16f);

    // sweep 2: accumulate messages; lane = output channel
    float acc = 0.f;
    for (int cb = beg; cb < end; cb += 64) {
        int m = min(64, end - cb);
        if (lane < m) {
            int s = csrc[cb + lane];
            srcl[lane] = s;
            float4 ss = ((const float4*)ssrc)[s];
            float e0 = ss.x + sd.x; e0 = e0 > 0.f ? e0 : 0.2f * e0;
            float e1 = ss.y + sd.y; e1 = e1 > 0.f ? e1 : 0.2f * e1;
            float e2 = ss.z + sd.z; e2 = e2 > 0.f ? e2 : 0.2f * e2;
            float e3 = ss.w + sd.w; e3 = e3 > 0.f ? e3 : 0.2f * e3;
            exl[lane * 4 + 0] = __expf(e0);
            exl[lane * 4 + 1] = __expf(e1);
            exl[lane * 4 + 2] = __expf(e2);
            exl[lane * 4 + 3] = __expf(e3);
        }
        __syncthreads();
        for (int j = 0; j < m; j++) {
            int s = srcl[j];
            acc += h[(size_t)s * HIDD + lane] * exl[j * 4 + hd];
        }
        __syncthreads();
    }
    float r = acc * inv_z + bias[lane];
    out[(size_t)n * HIDD + lane] = r > 0.f ? r : 0.f;
}

// ---------------- FC layers ----------------
// thread -> (node, 4 consecutive outputs); W staged in LDS.

template<int KDIM, int JDIM, bool RELU>
__global__ __launch_bounds__(256) void k_fc(
        const float* __restrict__ x, const float* __restrict__ W,
        const float* __restrict__ bias, float* __restrict__ out) {
    __shared__ float wl[KDIM * JDIM];
    for (int i = threadIdx.x; i < KDIM * JDIM / 4; i += 256)
        ((float4*)wl)[i] = ((const float4*)W)[i];
    __syncthreads();
    int qid = blockIdx.x * 256 + threadIdx.x;
    const int QPN = JDIM / 4;
    if (qid >= NN * QPN) return;
    int n  = qid / QPN;
    int j0 = (qid % QPN) * 4;
    const float* xr = x + (size_t)n * KDIM;
    float ax = 0.f, ay = 0.f, az = 0.f, aw = 0.f;
    #pragma unroll
    for (int k4 = 0; k4 < KDIM / 4; k4++) {
        float4 xv = ((const float4*)xr)[k4];
        float4 wa = *(const float4*)&wl[(k4 * 4 + 0) * JDIM + j0];
        float4 wb = *(const float4*)&wl[(k4 * 4 + 1) * JDIM + j0];
        float4 wc = *(const float4*)&wl[(k4 * 4 + 2) * JDIM + j0];
        float4 wd = *(const float4*)&wl[(k4 * 4 + 3) * JDIM + j0];
        ax += xv.x * wa.x + xv.y * wb.x + xv.z * wc.x + xv.w * wd.x;
        ay += xv.x * wa.y + xv.y * wb.y + xv.z * wc.y + xv.w * wd.y;
        az += xv.x * wa.z + xv.y * wb.z + xv.z * wc.z + xv.w * wd.z;
        aw += xv.x * wa.w + xv.y * wb.w + xv.z * wc.w + xv.w * wd.w;
    }
    ax += bias[j0]; ay += bias[j0 + 1]; az += bias[j0 + 2]; aw += bias[j0 + 3];
    if (RELU) {
        ax = ax > 0.f ? ax : 0.f; ay = ay > 0.f ? ay : 0.f;
        az = az > 0.f ? az : 0.f; aw = aw > 0.f ? aw : 0.f;
    }
    float4 r = {ax, ay, az, aw};
    *(float4*)(out + (size_t)n * JDIM + j0) = r;
}

// ---------------- launch ----------------

extern "C" void kernel_launch(void* const* d_in, const int* in_sizes, int n_in,
                              void* d_out, int out_size, void* d_ws, size_t ws_size,
                              hipStream_t stream) {
    const float* x   = (const float*)d_in[0];
    const int*   ei  = (const int*)d_in[1];
    const float* W0  = (const float*)d_in[2];
    const float* as0 = (const float*)d_in[3];
    const float* ad0 = (const float*)d_in[4];
    const float* b0  = (const float*)d_in[5];
    const float* W1  = (const float*)d_in[6];
    const float* as1 = (const float*)d_in[7];
    const float* ad1 = (const float*)d_in[8];
    const float* b1  = (const float*)d_in[9];
    const float* W2  = (const float*)d_in[10];
    const float* as2 = (const float*)d_in[11];
    const float* ad2 = (const float*)d_in[12];
    const float* b2  = (const float*)d_in[13];
    const float* fw1 = (const float*)d_in[14];
    const float* fb1 = (const float*)d_in[15];
    const float* fw2 = (const float*)d_in[16];
    const float* fb2 = (const float*)d_in[17];

    float* ws     = (float*)d_ws;
    float* h_buf  = ws;                        // N*64
    float* ssrc   = h_buf + (size_t)NN * HIDD; // N*4
    float* sdst   = ssrc + (size_t)NN * NHEADS;
    float* act    = sdst + (size_t)NN * NHEADS; // N*64
    float* fcb    = act + (size_t)NN * HIDD;    // N*160
    int*   deg    = (int*)(fcb + (size_t)NN * FCD);
    int*   rowptr = deg + NN;
    int*   woff   = rowptr + NN + 1;
    int*   csrc   = woff + NN;

    hipMemsetAsync(deg, 0, NN * sizeof(int), stream);
    k_count<<<(ETOT + 255) / 256, 256, 0, stream>>>(ei, deg);
    k_scan<<<1, 1024, 0, stream>>>(deg, rowptr, woff);
    k_scatter<<<(ETOT + 255) / 256, 256, 0, stream>>>(ei, woff, csrc);

    // layer 0
    k_gemm_scores<128><<<NN / 16, 256, 0, stream>>>(x, W0, as0, ad0, h_buf, ssrc, sdst);
    k_aggr<<<NN, 64, 0, stream>>>(h_buf, ssrc, sdst, rowptr, csrc, b0, act);
    // layer 1
    k_gemm_scores<64><<<NN / 16, 256, 0, stream>>>(act, W1, as1, ad1, h_buf, ssrc, sdst);
    k_aggr<<<NN, 64, 0, stream>>>(h_buf, ssrc, sdst, rowptr, csrc, b1, act);
    // layer 2
    k_gemm_scores<64><<<NN / 16, 256, 0, stream>>>(act, W2, as2, ad2, h_buf, ssrc, sdst);
    k_aggr<<<NN, 64, 0, stream>>>(h_buf, ssrc, sdst, rowptr, csrc, b2, act);

    // FC head
    k_fc<64, 160, true><<<(NN * (FCD / 4) + 255) / 256, 256, 0, stream>>>(act, fw1, fb1, fcb);
    k_fc<160, 64, false><<<(NN * (OUTD / 4) + 255) / 256, 256, 0, stream>>>(fcb, fw2, fb2, (float*)d_out);
}

// Round 2
// 349.147 us; speedup vs baseline: 1.2816x; 1.2816x over previous
//
#include <hip/hip_runtime.h>

#define NN 50000
#define EE 800000
#define ETOT (EE + NN)          // 850000
#define HIDD 64
#define NHEADS 4
#define GDIM 16
#define FCD 160
#define OUTD 64
#define NBLK ((NN + 255) / 256) // 196

// ---------------- CSR build ----------------

__global__ void k_count(const int* __restrict__ ei, int* __restrict__ deg) {
    int i = blockIdx.x * 256 + threadIdx.x;
    if (i >= ETOT) return;
    int dst = (i < EE) ? ei[EE + i] : (i - EE);
    atomicAdd(&deg[dst], 1);
}

// per-block exclusive scan; writes block sums
__global__ __launch_bounds__(256) void k_bscan(const int* __restrict__ deg,
                                               int* __restrict__ rowptr,
                                               int* __restrict__ bsum) {
    int t = threadIdx.x;
    int i = blockIdx.x * 256 + t;
    int v = (i < NN) ? deg[i] : 0;
    int lane = t & 63, w = t >> 6;
    int x = v;
    #pragma unroll
    for (int off = 1; off < 64; off <<= 1) {
        int y = __shfl_up(x, off);
        if (lane >= off) x += y;
    }
    __shared__ int wsum[4];
    if (lane == 63) wsum[w] = x;
    __syncthreads();
    int add = 0;
    #pragma unroll
    for (int k = 0; k < 4; k++) add += (k < w) ? wsum[k] : 0;
    int incl = x + add;
    if (i < NN) rowptr[i] = incl - v;   // block-local exclusive
    if (t == 255) bsum[blockIdx.x] = incl;
}

// exclusive scan of the 196 block sums (one block)
__global__ __launch_bounds__(256) void k_scanbs(int* __restrict__ bsum) {
    int t = threadIdx.x;
    int v = (t < NBLK) ? bsum[t] : 0;
    int lane = t & 63, w = t >> 6;
    int x = v;
    #pragma unroll
    for (int off = 1; off < 64; off <<= 1) {
        int y = __shfl_up(x, off);
        if (lane >= off) x += y;
    }
    __shared__ int wsum[4];
    if (lane == 63) wsum[w] = x;
    __syncthreads();
    int add = 0;
    #pragma unroll
    for (int k = 0; k < 4; k++) add += (k < w) ? wsum[k] : 0;
    if (t < NBLK) bsum[t] = x + add - v;  // exclusive
}

__global__ __launch_bounds__(256) void k_addoff(const int* __restrict__ bsum,
                                                int* __restrict__ rowptr,
                                                int* __restrict__ woff) {
    int i = blockIdx.x * 256 + threadIdx.x;
    if (i < NN) {
        int r = rowptr[i] + bsum[blockIdx.x];
        rowptr[i] = r;
        woff[i] = r;
    }
    if (i == NN) rowptr[NN] = ETOT;
}

__global__ void k_scatter(const int* __restrict__ ei, int* __restrict__ woff,
                          int* __restrict__ csrc) {
    int i = blockIdx.x * 256 + threadIdx.x;
    if (i >= ETOT) return;
    int src, dst;
    if (i < EE) { src = ei[i]; dst = ei[EE + i]; }
    else { src = dst = i - EE; }
    int pos = atomicAdd(&woff[dst], 1);
    csrc[pos] = src;
}

// ---------------- GEMM h = x@W + per-node attention scores ----------------
// block = 256 threads, 16 nodes/block, each thread 4 consecutive outputs.

template<int FIN>
__global__ __launch_bounds__(256) void k_gemm_scores(
        const float* __restrict__ x, const float* __restrict__ W,
        const float* __restrict__ a_src, const float* __restrict__ a_dst,
        float* __restrict__ h, float* __restrict__ ssrc, float* __restrict__ sdst) {
    __shared__ float wlds[FIN * HIDD];
    __shared__ float xlds[16 * FIN];
    int t = threadIdx.x;
    int nb = blockIdx.x * 16;
    for (int i = t; i < FIN * HIDD / 4; i += 256)
        ((float4*)wlds)[i] = ((const float4*)W)[i];
    for (int i = t; i < 16 * FIN / 4; i += 256)
        ((float4*)xlds)[i] = ((const float4*)(x + (size_t)nb * FIN))[i];
    __syncthreads();

    int nl = t >> 4;          // local node 0..15
    int q  = t & 15;          // j-quad 0..15
    int j0 = q * 4;
    float a0 = 0.f, a1 = 0.f, a2 = 0.f, a3 = 0.f;
    const float4* wl4 = (const float4*)wlds;
    const float4* xl4 = (const float4*)(xlds + nl * FIN);
    #pragma unroll
    for (int k4 = 0; k4 < FIN / 4; k4++) {
        float4 xv = xl4[k4];
        float4 wa = wl4[(k4 * 4 + 0) * 16 + q];
        float4 wb = wl4[(k4 * 4 + 1) * 16 + q];
        float4 wc = wl4[(k4 * 4 + 2) * 16 + q];
        float4 wd = wl4[(k4 * 4 + 3) * 16 + q];
        a0 += xv.x * wa.x + xv.y * wb.x + xv.z * wc.x + xv.w * wd.x;
        a1 += xv.x * wa.y + xv.y * wb.y + xv.z * wc.y + xv.w * wd.y;
        a2 += xv.x * wa.z + xv.y * wb.z + xv.z * wc.z + xv.w * wd.z;
        a3 += xv.x * wa.w + xv.y * wb.w + xv.z * wc.w + xv.w * wd.w;
    }
    int n = nb + nl;
    float4 hv = {a0, a1, a2, a3};
    *(float4*)(h + (size_t)n * HIDD + j0) = hv;

    float vs = a0 * a_src[j0] + a1 * a_src[j0 + 1] + a2 * a_src[j0 + 2] + a3 * a_src[j0 + 3];
    float vd = a0 * a_dst[j0] + a1 * a_dst[j0 + 1] + a2 * a_dst[j0 + 2] + a3 * a_dst[j0 + 3];
    vs += __shfl_xor(vs, 1); vs += __shfl_xor(vs, 2);
    vd += __shfl_xor(vd, 1); vd += __shfl_xor(vd, 2);
    if ((q & 3) == 0) {
        ssrc[n * NHEADS + (q >> 2)] = vs;
        sdst[n * NHEADS + (q >> 2)] = vd;
    }
}

// ---------------- per-destination aggregation (1 wave per node) ----------------

__global__ __launch_bounds__(64) void k_aggr(
        const float* __restrict__ h, const float* __restrict__ ssrc,
        const float* __restrict__ sdst, const int* __restrict__ rowptr,
        const int* __restrict__ csrc, const float* __restrict__ bias,
        float* __restrict__ out) {
    __shared__ float exl[64 * 4];
    __shared__ int srcl[64];
    int n = blockIdx.x;
    int lane = threadIdx.x;
    int hd = lane >> 4;
    int beg = rowptr[n], end = rowptr[n + 1];
    float4 sd = ((const float4*)sdst)[n];

    // sweep 1: softmax denominator per head (max-subtraction cancels in alpha; scores are O(1))
    float z0 = 0.f, z1 = 0.f, z2 = 0.f, z3 = 0.f;
    for (int i = beg + lane; i < end; i += 64) {
        int s = csrc[i];
        float4 ss = ((const float4*)ssrc)[s];
        float e0 = ss.x + sd.x; e0 = e0 > 0.f ? e0 : 0.2f * e0; z0 += __expf(e0);
        float e1 = ss.y + sd.y; e1 = e1 > 0.f ? e1 : 0.2f * e1; z1 += __expf(e1);
        float e2 = ss.z + sd.z; e2 = e2 > 0.f ? e2 : 0.2f * e2; z2 += __expf(e2);
        float e3 = ss.w + sd.w; e3 = e3 > 0.f ? e3 : 0.2f * e3; z3 += __expf(e3);
    }
    for (int m = 1; m < 64; m <<= 1) {
        z0 += __shfl_xor(z0, m); z1 += __shfl_xor(z1, m);
        z2 += __shfl_xor(z2, m); z3 += __shfl_xor(z3, m);
    }
    float zh = (hd == 0) ? z0 : (hd == 1) ? z1 : (hd == 2) ? z2 : z3;
    float inv_z = 1.0f / (zh + 1e-16f);

    // sweep 2: accumulate messages; lane = output channel
    float acc = 0.f;
    for (int cb = beg; cb < end; cb += 64) {
        int m = min(64, end - cb);
        if (lane < m) {
            int s = csrc[cb + lane];
            srcl[lane] = s;
            float4 ss = ((const float4*)ssrc)[s];
            float e0 = ss.x + sd.x; e0 = e0 > 0.f ? e0 : 0.2f * e0;
            float e1 = ss.y + sd.y; e1 = e1 > 0.f ? e1 : 0.2f * e1;
            float e2 = ss.z + sd.z; e2 = e2 > 0.f ? e2 : 0.2f * e2;
            float e3 = ss.w + sd.w; e3 = e3 > 0.f ? e3 : 0.2f * e3;
            exl[lane * 4 + 0] = __expf(e0);
            exl[lane * 4 + 1] = __expf(e1);
            exl[lane * 4 + 2] = __expf(e2);
            exl[lane * 4 + 3] = __expf(e3);
        }
        __syncthreads();
        for (int j = 0; j < m; j++) {
            int s = srcl[j];
            acc += h[(size_t)s * HIDD + lane] * exl[j * 4 + hd];
        }
        __syncthreads();
    }
    float r = acc * inv_z + bias[lane];
    out[(size_t)n * HIDD + lane] = r > 0.f ? r : 0.f;
}

// ---------------- FC layers ----------------
// thread -> (node, 4 consecutive outputs); W staged in LDS.

template<int KDIM, int JDIM, bool RELU>
__global__ __launch_bounds__(256) void k_fc(
        const float* __restrict__ x, const float* __restrict__ W,
        const float* __restrict__ bias, float* __restrict__ out) {
    __shared__ float wl[KDIM * JDIM];
    for (int i = threadIdx.x; i < KDIM * JDIM / 4; i += 256)
        ((float4*)wl)[i] = ((const float4*)W)[i];
    __syncthreads();
    int qid = blockIdx.x * 256 + threadIdx.x;
    const int QPN = JDIM / 4;
    if (qid >= NN * QPN) return;
    int n  = qid / QPN;
    int j0 = (qid % QPN) * 4;
    const float* xr = x + (size_t)n * KDIM;
    float ax = 0.f, ay = 0.f, az = 0.f, aw = 0.f;
    #pragma unroll
    for (int k4 = 0; k4 < KDIM / 4; k4++) {
        float4 xv = ((const float4*)xr)[k4];
        float4 wa = *(const float4*)&wl[(k4 * 4 + 0) * JDIM + j0];
        float4 wb = *(const float4*)&wl[(k4 * 4 + 1) * JDIM + j0];
        float4 wc = *(const float4*)&wl[(k4 * 4 + 2) * JDIM + j0];
        float4 wd = *(const float4*)&wl[(k4 * 4 + 3) * JDIM + j0];
        ax += xv.x * wa.x + xv.y * wb.x + xv.z * wc.x + xv.w * wd.x;
        ay += xv.x * wa.y + xv.y * wb.y + xv.z * wc.y + xv.w * wd.y;
        az += xv.x * wa.z + xv.y * wb.z + xv.z * wc.z + xv.w * wd.z;
        aw += xv.x * wa.w + xv.y * wb.w + xv.z * wc.w + xv.w * wd.w;
    }
    ax += bias[j0]; ay += bias[j0 + 1]; az += bias[j0 + 2]; aw += bias[j0 + 3];
    if (RELU) {
        ax = ax > 0.f ? ax : 0.f; ay = ay > 0.f ? ay : 0.f;
        az = az > 0.f ? az : 0.f; aw = aw > 0.f ? aw : 0.f;
    }
    float4 r = {ax, ay, az, aw};
    *(float4*)(out + (size_t)n * JDIM + j0) = r;
}

// ---------------- launch ----------------

extern "C" void kernel_launch(void* const* d_in, const int* in_sizes, int n_in,
                              void* d_out, int out_size, void* d_ws, size_t ws_size,
                              hipStream_t stream) {
    const float* x   = (const float*)d_in[0];
    const int*   ei  = (const int*)d_in[1];
    const float* W0  = (const float*)d_in[2];
    const float* as0 = (const float*)d_in[3];
    const float* ad0 = (const float*)d_in[4];
    const float* b0  = (const float*)d_in[5];
    const float* W1  = (const float*)d_in[6];
    const float* as1 = (const float*)d_in[7];
    const float* ad1 = (const float*)d_in[8];
    const float* b1  = (const float*)d_in[9];
    const float* W2  = (const float*)d_in[10];
    const float* as2 = (const float*)d_in[11];
    const float* ad2 = (const float*)d_in[12];
    const float* b2  = (const float*)d_in[13];
    const float* fw1 = (const float*)d_in[14];
    const float* fb1 = (const float*)d_in[15];
    const float* fw2 = (const float*)d_in[16];
    const float* fb2 = (const float*)d_in[17];

    float* ws     = (float*)d_ws;
    float* h_buf  = ws;                        // N*64
    float* ssrc   = h_buf + (size_t)NN * HIDD; // N*4
    float* sdst   = ssrc + (size_t)NN * NHEADS;
    float* act    = sdst + (size_t)NN * NHEADS; // N*64
    float* fcb    = act + (size_t)NN * HIDD;    // N*160
    int*   deg    = (int*)(fcb + (size_t)NN * FCD);
    int*   rowptr = deg + NN;
    int*   woff   = rowptr + NN + 1;
    int*   csrc   = woff + NN;
    int*   bsum   = csrc + ETOT;

    hipMemsetAsync(deg, 0, NN * sizeof(int), stream);
    k_count<<<(ETOT + 255) / 256, 256, 0, stream>>>(ei, deg);
    k_bscan<<<NBLK, 256, 0, stream>>>(deg, rowptr, bsum);
    k_scanbs<<<1, 256, 0, stream>>>(bsum);
    k_addoff<<<NBLK, 256, 0, stream>>>(bsum, rowptr, woff);
    k_scatter<<<(ETOT + 255) / 256, 256, 0, stream>>>(ei, woff, csrc);

    // layer 0
    k_gemm_scores<128><<<NN / 16, 256, 0, stream>>>(x, W0, as0, ad0, h_buf, ssrc, sdst);
    k_aggr<<<NN, 64, 0, stream>>>(h_buf, ssrc, sdst, rowptr, csrc, b0, act);
    // layer 1
    k_gemm_scores<64><<<NN / 16, 256, 0, stream>>>(act, W1, as1, ad1, h_buf, ssrc, sdst);
    k_aggr<<<NN, 64, 0, stream>>>(h_buf, ssrc, sdst, rowptr, csrc, b1, act);
    // layer 2
    k_gemm_scores<64><<<NN / 16, 256, 0, stream>>>(act, W2, as2, ad2, h_buf, ssrc, sdst);
    k_aggr<<<NN, 64, 0, stream>>>(h_buf, ssrc, sdst, rowptr, csrc, b2, act);

    // FC head
    k_fc<64, 160, true><<<(NN * (FCD / 4) + 255) / 256, 256, 0, stream>>>(act, fw1, fb1, fcb);
    k_fc<160, 64, false><<<(NN * (OUTD / 4) + 255) / 256, 256, 0, stream>>>(fcb, fw2, fb2, (float*)d_out);
}

// Round 3
// 298.512 us; speedup vs baseline: 1.4990x; 1.1696x over previous
//
#include <hip/hip_runtime.h>

#define NN 50000
#define EE 800000
#define ETOT (EE + NN)          // 850000
#define HIDD 64
#define NHEADS 4
#define FCD 160
#define OUTD 64

#define NBKT 196                // dst>>8 -> 196 buckets of 256 dst nodes
#define CHUNK 4096
#define NEBLK ((ETOT + CHUNK - 1) / CHUNK)   // 208

// ---------------- CSR build: two-level bucketed counting sort ----------------

// pass 1: per-chunk LDS histogram of dst buckets; reserve intra-bucket ranges
__global__ __launch_bounds__(256) void k_hist(const int* __restrict__ ei,
                                              int* __restrict__ bucket_count,
                                              int* __restrict__ bbase) {
    __shared__ int hist[NBKT];
    int t = threadIdx.x;
    for (int i = t; i < NBKT; i += 256) hist[i] = 0;
    __syncthreads();
    int base = blockIdx.x * CHUNK;
    for (int k = t; k < CHUNK; k += 256) {
        int i = base + k;
        if (i < ETOT) {
            int dst = (i < EE) ? ei[EE + i] : (i - EE);
            atomicAdd(&hist[dst >> 8], 1);
        }
    }
    __syncthreads();
    for (int b = t; b < NBKT; b += 256) {
        int c = hist[b];
        int r = c ? atomicAdd(&bucket_count[b], c) : 0;
        bbase[blockIdx.x * NBKT + b] = r;
    }
}

// pass 2: exclusive scan of the 196 bucket counts
__global__ __launch_bounds__(256) void k_scanb(const int* __restrict__ bucket_count,
                                               int* __restrict__ bucket_start) {
    int t = threadIdx.x;
    int v = (t < NBKT) ? bucket_count[t] : 0;
    int lane = t & 63, w = t >> 6;
    int x = v;
    #pragma unroll
    for (int off = 1; off < 64; off <<= 1) {
        int y = __shfl_up(x, off);
        if (lane >= off) x += y;
    }
    __shared__ int wsum[4];
    if (lane == 63) wsum[w] = x;
    __syncthreads();
    int add = 0;
    #pragma unroll
    for (int k = 0; k < 4; k++) add += (k < w) ? wsum[k] : 0;
    if (t < NBKT) bucket_start[t] = x + add - v;
    if (t == 0) bucket_start[NBKT] = ETOT;
}

// pass 3: write (src,dst) pairs grouped by bucket; per-block runs are contiguous
__global__ __launch_bounds__(256) void k_binwrite(const int* __restrict__ ei,
                                                  const int* __restrict__ bucket_start,
                                                  const int* __restrict__ bbase,
                                                  uint2* __restrict__ binned) {
    __shared__ int hist[NBKT];
    __shared__ int sbase[NBKT];
    __shared__ int cur[NBKT];
    __shared__ int wsum[4];
    int t = threadIdx.x;
    for (int i = t; i < NBKT; i += 256) hist[i] = 0;
    __syncthreads();
    int base = blockIdx.x * CHUNK;
    for (int k = t; k < CHUNK; k += 256) {
        int i = base + k;
        if (i < ETOT) {
            int dst = (i < EE) ? ei[EE + i] : (i - EE);
            atomicAdd(&hist[dst >> 8], 1);
        }
    }
    __syncthreads();
    {   // exclusive scan of hist -> local group offsets
        int v = (t < NBKT) ? hist[t] : 0;
        int lane = t & 63, w = t >> 6;
        int x = v;
        #pragma unroll
        for (int off = 1; off < 64; off <<= 1) {
            int y = __shfl_up(x, off);
            if (lane >= off) x += y;
        }
        if (lane == 63) wsum[w] = x;
        __syncthreads();
        int add = 0;
        #pragma unroll
        for (int k = 0; k < 4; k++) add += (k < w) ? wsum[k] : 0;
        int excl = x + add - v;
        if (t < NBKT) {
            sbase[t] = bucket_start[t] + bbase[blockIdx.x * NBKT + t] - excl;
            cur[t] = excl;
        }
    }
    __syncthreads();
    for (int k = t; k < CHUNK; k += 256) {
        int i = base + k;
        if (i < ETOT) {
            int src, dst;
            if (i < EE) { src = ei[i]; dst = ei[EE + i]; }
            else { src = dst = i - EE; }
            int b = dst >> 8;
            int p = atomicAdd(&cur[b], 1);
            binned[sbase[b] + p] = make_uint2((unsigned)src, (unsigned)dst);
        }
    }
}

// pass 4: one block per bucket -> rowptr + final csrc (all writes bucket-local)
__global__ __launch_bounds__(256) void k_csr_final(const int* __restrict__ bucket_start,
                                                   const uint2* __restrict__ binned,
                                                   int* __restrict__ rowptr,
                                                   int* __restrict__ csrc) {
    __shared__ int hist[256];
    __shared__ int cur[256];
    __shared__ int wsum[4];
    int b = blockIdx.x;
    int t = threadIdx.x;
    int s0 = bucket_start[b], s1 = bucket_start[b + 1];
    int cnt = s1 - s0;
    hist[t] = 0;
    __syncthreads();
    for (int k = t; k < cnt; k += 256) {
        int dst = (int)binned[s0 + k].y;
        atomicAdd(&hist[dst & 255], 1);
    }
    __syncthreads();
    int v = hist[t];
    int lane = t & 63, w = t >> 6;
    int x = v;
    #pragma unroll
    for (int off = 1; off < 64; off <<= 1) {
        int y = __shfl_up(x, off);
        if (lane >= off) x += y;
    }
    if (lane == 63) wsum[w] = x;
    __syncthreads();
    int add = 0;
    #pragma unroll
    for (int k = 0; k < 4; k++) add += (k < w) ? wsum[k] : 0;
    int excl = x + add - v;
    int n = (b << 8) + t;
    if (n < NN) rowptr[n] = s0 + excl;
    if (b == 0 && t == 0) rowptr[NN] = ETOT;
    cur[t] = s0 + excl;
    __syncthreads();
    for (int k = t; k < cnt; k += 256) {
        uint2 pr = binned[s0 + k];
        int p = atomicAdd(&cur[pr.y & 255], 1);
        csrc[p] = (int)pr.x;
    }
}

// ---------------- GEMM h = x@W + per-node attention scores ----------------
// block = 256 threads, 16 nodes/block, each thread 4 consecutive outputs.

template<int FIN>
__global__ __launch_bounds__(256) void k_gemm_scores(
        const float* __restrict__ x, const float* __restrict__ W,
        const float* __restrict__ a_src, const float* __restrict__ a_dst,
        float* __restrict__ h, float* __restrict__ ssrc, float* __restrict__ sdst) {
    __shared__ float wlds[FIN * HIDD];
    __shared__ float xlds[16 * FIN];
    int t = threadIdx.x;
    int nb = blockIdx.x * 16;
    for (int i = t; i < FIN * HIDD / 4; i += 256)
        ((float4*)wlds)[i] = ((const float4*)W)[i];
    for (int i = t; i < 16 * FIN / 4; i += 256)
        ((float4*)xlds)[i] = ((const float4*)(x + (size_t)nb * FIN))[i];
    __syncthreads();

    int nl = t >> 4;          // local node 0..15
    int q  = t & 15;          // j-quad 0..15
    int j0 = q * 4;
    float a0 = 0.f, a1 = 0.f, a2 = 0.f, a3 = 0.f;
    const float4* wl4 = (const float4*)wlds;
    const float4* xl4 = (const float4*)(xlds + nl * FIN);
    #pragma unroll
    for (int k4 = 0; k4 < FIN / 4; k4++) {
        float4 xv = xl4[k4];
        float4 wa = wl4[(k4 * 4 + 0) * 16 + q];
        float4 wb = wl4[(k4 * 4 + 1) * 16 + q];
        float4 wc = wl4[(k4 * 4 + 2) * 16 + q];
        float4 wd = wl4[(k4 * 4 + 3) * 16 + q];
        a0 += xv.x * wa.x + xv.y * wb.x + xv.z * wc.x + xv.w * wd.x;
        a1 += xv.x * wa.y + xv.y * wb.y + xv.z * wc.y + xv.w * wd.y;
        a2 += xv.x * wa.z + xv.y * wb.z + xv.z * wc.z + xv.w * wd.z;
        a3 += xv.x * wa.w + xv.y * wb.w + xv.z * wc.w + xv.w * wd.w;
    }
    int n = nb + nl;
    float4 hv = {a0, a1, a2, a3};
    *(float4*)(h + (size_t)n * HIDD + j0) = hv;

    float vs = a0 * a_src[j0] + a1 * a_src[j0 + 1] + a2 * a_src[j0 + 2] + a3 * a_src[j0 + 3];
    float vd = a0 * a_dst[j0] + a1 * a_dst[j0 + 1] + a2 * a_dst[j0 + 2] + a3 * a_dst[j0 + 3];
    vs += __shfl_xor(vs, 1); vs += __shfl_xor(vs, 2);
    vd += __shfl_xor(vd, 1); vd += __shfl_xor(vd, 2);
    if ((q & 3) == 0) {
        ssrc[n * NHEADS + (q >> 2)] = vs;
        sdst[n * NHEADS + (q >> 2)] = vd;
    }
}

// ---------------- per-destination aggregation (1 wave per node) ----------------

__global__ __launch_bounds__(64) void k_aggr(
        const float* __restrict__ h, const float* __restrict__ ssrc,
        const float* __restrict__ sdst, const int* __restrict__ rowptr,
        const int* __restrict__ csrc, const float* __restrict__ bias,
        float* __restrict__ out) {
    __shared__ float exl[64 * 4];
    __shared__ int srcl[64];
    int n = blockIdx.x;
    int lane = threadIdx.x;
    int hd = lane >> 4;
    int beg = rowptr[n], end = rowptr[n + 1];
    float4 sd = ((const float4*)sdst)[n];

    // sweep 1: softmax denominator per head (max-subtraction cancels in alpha; scores are O(1))
    float z0 = 0.f, z1 = 0.f, z2 = 0.f, z3 = 0.f;
    for (int i = beg + lane; i < end; i += 64) {
        int s = csrc[i];
        float4 ss = ((const float4*)ssrc)[s];
        float e0 = ss.x + sd.x; e0 = e0 > 0.f ? e0 : 0.2f * e0; z0 += __expf(e0);
        float e1 = ss.y + sd.y; e1 = e1 > 0.f ? e1 : 0.2f * e1; z1 += __expf(e1);
        float e2 = ss.z + sd.z; e2 = e2 > 0.f ? e2 : 0.2f * e2; z2 += __expf(e2);
        float e3 = ss.w + sd.w; e3 = e3 > 0.f ? e3 : 0.2f * e3; z3 += __expf(e3);
    }
    for (int m = 1; m < 64; m <<= 1) {
        z0 += __shfl_xor(z0, m); z1 += __shfl_xor(z1, m);
        z2 += __shfl_xor(z2, m); z3 += __shfl_xor(z3, m);
    }
    float zh = (hd == 0) ? z0 : (hd == 1) ? z1 : (hd == 2) ? z2 : z3;
    float inv_z = 1.0f / (zh + 1e-16f);

    // sweep 2: accumulate messages; lane = output channel
    float acc = 0.f;
    for (int cb = beg; cb < end; cb += 64) {
        int m = min(64, end - cb);
        if (lane < m) {
            int s = csrc[cb + lane];
            srcl[lane] = s;
            float4 ss = ((const float4*)ssrc)[s];
            float e0 = ss.x + sd.x; e0 = e0 > 0.f ? e0 : 0.2f * e0;
            float e1 = ss.y + sd.y; e1 = e1 > 0.f ? e1 : 0.2f * e1;
            float e2 = ss.z + sd.z; e2 = e2 > 0.f ? e2 : 0.2f * e2;
            float e3 = ss.w + sd.w; e3 = e3 > 0.f ? e3 : 0.2f * e3;
            exl[lane * 4 + 0] = __expf(e0);
            exl[lane * 4 + 1] = __expf(e1);
            exl[lane * 4 + 2] = __expf(e2);
            exl[lane * 4 + 3] = __expf(e3);
        }
        __syncthreads();
        for (int j = 0; j < m; j++) {
            int s = srcl[j];
            acc += h[(size_t)s * HIDD + lane] * exl[j * 4 + hd];
        }
        __syncthreads();
    }
    float r = acc * inv_z + bias[lane];
    out[(size_t)n * HIDD + lane] = r > 0.f ? r : 0.f;
}

// ---------------- FC layers ----------------

template<int KDIM, int JDIM, bool RELU>
__global__ __launch_bounds__(256) void k_fc(
        const float* __restrict__ x, const float* __restrict__ W,
        const float* __restrict__ bias, float* __restrict__ out) {
    __shared__ float wl[KDIM * JDIM];
    for (int i = threadIdx.x; i < KDIM * JDIM / 4; i += 256)
        ((float4*)wl)[i] = ((const float4*)W)[i];
    __syncthreads();
    int qid = blockIdx.x * 256 + threadIdx.x;
    const int QPN = JDIM / 4;
    if (qid >= NN * QPN) return;
    int n  = qid / QPN;
    int j0 = (qid % QPN) * 4;
    const float* xr = x + (size_t)n * KDIM;
    float ax = 0.f, ay = 0.f, az = 0.f, aw = 0.f;
    #pragma unroll
    for (int k4 = 0; k4 < KDIM / 4; k4++) {
        float4 xv = ((const float4*)xr)[k4];
        float4 wa = *(const float4*)&wl[(k4 * 4 + 0) * JDIM + j0];
        float4 wb = *(const float4*)&wl[(k4 * 4 + 1) * JDIM + j0];
        float4 wc = *(const float4*)&wl[(k4 * 4 + 2) * JDIM + j0];
        float4 wd = *(const float4*)&wl[(k4 * 4 + 3) * JDIM + j0];
        ax += xv.x * wa.x + xv.y * wb.x + xv.z * wc.x + xv.w * wd.x;
        ay += xv.x * wa.y + xv.y * wb.y + xv.z * wc.y + xv.w * wd.y;
        az += xv.x * wa.z + xv.y * wb.z + xv.z * wc.z + xv.w * wd.z;
        aw += xv.x * wa.w + xv.y * wb.w + xv.z * wc.w + xv.w * wd.w;
    }
    ax += bias[j0]; ay += bias[j0 + 1]; az += bias[j0 + 2]; aw += bias[j0 + 3];
    if (RELU) {
        ax = ax > 0.f ? ax : 0.f; ay = ay > 0.f ? ay : 0.f;
        az = az > 0.f ? az : 0.f; aw = aw > 0.f ? aw : 0.f;
    }
    float4 r = {ax, ay, az, aw};
    *(float4*)(out + (size_t)n * JDIM + j0) = r;
}

// ---------------- launch ----------------

extern "C" void kernel_launch(void* const* d_in, const int* in_sizes, int n_in,
                              void* d_out, int out_size, void* d_ws, size_t ws_size,
                              hipStream_t stream) {
    const float* x   = (const float*)d_in[0];
    const int*   ei  = (const int*)d_in[1];
    const float* W0  = (const float*)d_in[2];
    const float* as0 = (const float*)d_in[3];
    const float* ad0 = (const float*)d_in[4];
    const float* b0  = (const float*)d_in[5];
    const float* W1  = (const float*)d_in[6];
    const float* as1 = (const float*)d_in[7];
    const float* ad1 = (const float*)d_in[8];
    const float* b1  = (const float*)d_in[9];
    const float* W2  = (const float*)d_in[10];
    const float* as2 = (const float*)d_in[11];
    const float* ad2 = (const float*)d_in[12];
    const float* b2  = (const float*)d_in[13];
    const float* fw1 = (const float*)d_in[14];
    const float* fb1 = (const float*)d_in[15];
    const float* fw2 = (const float*)d_in[16];
    const float* fb2 = (const float*)d_in[17];

    float* ws     = (float*)d_ws;
    float* h_buf  = ws;                          // N*64
    float* ssrc   = h_buf + (size_t)NN * HIDD;   // N*4
    float* sdst   = ssrc + (size_t)NN * NHEADS;  // N*4
    float* act    = sdst + (size_t)NN * NHEADS;  // N*64
    float* fcb    = act + (size_t)NN * HIDD;     // N*160 (FC scratch; binned aliases this)
    int*   rowptr = (int*)(fcb + (size_t)NN * FCD); // N+1
    int*   csrc   = rowptr + NN + 1;             // ETOT
    int*   bbase  = csrc + ETOT;                 // NEBLK*NBKT
    int*   bucket_count = bbase + NEBLK * NBKT;  // NBKT
    int*   bucket_start = bucket_count + NBKT;   // NBKT+1
    uint2* binned = (uint2*)fcb;                 // ETOT pairs (8B) <= N*160*4 bytes

    hipMemsetAsync(bucket_count, 0, NBKT * sizeof(int), stream);
    k_hist<<<NEBLK, 256, 0, stream>>>(ei, bucket_count, bbase);
    k_scanb<<<1, 256, 0, stream>>>(bucket_count, bucket_start);
    k_binwrite<<<NEBLK, 256, 0, stream>>>(ei, bucket_start, bbase, binned);
    k_csr_final<<<NBKT, 256, 0, stream>>>(bucket_start, binned, rowptr, csrc);

    // layer 0
    k_gemm_scores<128><<<NN / 16, 256, 0, stream>>>(x, W0, as0, ad0, h_buf, ssrc, sdst);
    k_aggr<<<NN, 64, 0, stream>>>(h_buf, ssrc, sdst, rowptr, csrc, b0, act);
    // layer 1
    k_gemm_scores<64><<<NN / 16, 256, 0, stream>>>(act, W1, as1, ad1, h_buf, ssrc, sdst);
    k_aggr<<<NN, 64, 0, stream>>>(h_buf, ssrc, sdst, rowptr, csrc, b1, act);
    // layer 2
    k_gemm_scores<64><<<NN / 16, 256, 0, stream>>>(act, W2, as2, ad2, h_buf, ssrc, sdst);
    k_aggr<<<NN, 64, 0, stream>>>(h_buf, ssrc, sdst, rowptr, csrc, b2, act);

    // FC head
    k_fc<64, 160, true><<<(NN * (FCD / 4) + 255) / 256, 256, 0, stream>>>(act, fw1, fb1, fcb);
    k_fc<160, 64, false><<<(NN * (OUTD / 4) + 255) / 256, 256, 0, stream>>>(fcb, fw2, fb2, (float*)d_out);
}

// Round 4
// 286.256 us; speedup vs baseline: 1.5631x; 1.0428x over previous
//
#include <hip/hip_runtime.h>

#define NN 50000
#define EE 800000
#define ETOT (EE + NN)          // 850000
#define HIDD 64
#define NHEADS 4
#define FCD 160
#define OUTD 64

#define NBKT 196                // dst>>8 -> 196 buckets of 256 dst nodes
#define CHUNK 4096
#define NEBLK ((ETOT + CHUNK - 1) / CHUNK)   // 208
#define NFCB ((NN + 63) / 64)   // 782

// ---------------- CSR build: two-level bucketed counting sort ----------------

__global__ __launch_bounds__(256) void k_hist(const int* __restrict__ ei,
                                              int* __restrict__ bucket_count,
                                              int* __restrict__ bbase) {
    __shared__ int hist[NBKT];
    int t = threadIdx.x;
    for (int i = t; i < NBKT; i += 256) hist[i] = 0;
    __syncthreads();
    int base = blockIdx.x * CHUNK;
    for (int k = t; k < CHUNK; k += 256) {
        int i = base + k;
        if (i < ETOT) {
            int dst = (i < EE) ? ei[EE + i] : (i - EE);
            atomicAdd(&hist[dst >> 8], 1);
        }
    }
    __syncthreads();
    for (int b = t; b < NBKT; b += 256) {
        int c = hist[b];
        int r = c ? atomicAdd(&bucket_count[b], c) : 0;
        bbase[blockIdx.x * NBKT + b] = r;
    }
}

__global__ __launch_bounds__(256) void k_scanb(const int* __restrict__ bucket_count,
                                               int* __restrict__ bucket_start) {
    int t = threadIdx.x;
    int v = (t < NBKT) ? bucket_count[t] : 0;
    int lane = t & 63, w = t >> 6;
    int x = v;
    #pragma unroll
    for (int off = 1; off < 64; off <<= 1) {
        int y = __shfl_up(x, off);
        if (lane >= off) x += y;
    }
    __shared__ int wsum[4];
    if (lane == 63) wsum[w] = x;
    __syncthreads();
    int add = 0;
    #pragma unroll
    for (int k = 0; k < 4; k++) add += (k < w) ? wsum[k] : 0;
    if (t < NBKT) bucket_start[t] = x + add - v;
    if (t == 0) bucket_start[NBKT] = ETOT;
}

__global__ __launch_bounds__(256) void k_binwrite(const int* __restrict__ ei,
                                                  const int* __restrict__ bucket_start,
                                                  const int* __restrict__ bbase,
                                                  uint2* __restrict__ binned) {
    __shared__ int hist[NBKT];
    __shared__ int sbase[NBKT];
    __shared__ int cur[NBKT];
    __shared__ int wsum[4];
    int t = threadIdx.x;
    for (int i = t; i < NBKT; i += 256) hist[i] = 0;
    __syncthreads();
    int base = blockIdx.x * CHUNK;
    for (int k = t; k < CHUNK; k += 256) {
        int i = base + k;
        if (i < ETOT) {
            int dst = (i < EE) ? ei[EE + i] : (i - EE);
            atomicAdd(&hist[dst >> 8], 1);
        }
    }
    __syncthreads();
    {
        int v = (t < NBKT) ? hist[t] : 0;
        int lane = t & 63, w = t >> 6;
        int x = v;
        #pragma unroll
        for (int off = 1; off < 64; off <<= 1) {
            int y = __shfl_up(x, off);
            if (lane >= off) x += y;
        }
        if (lane == 63) wsum[w] = x;
        __syncthreads();
        int add = 0;
        #pragma unroll
        for (int k = 0; k < 4; k++) add += (k < w) ? wsum[k] : 0;
        int excl = x + add - v;
        if (t < NBKT) {
            sbase[t] = bucket_start[t] + bbase[blockIdx.x * NBKT + t] - excl;
            cur[t] = excl;
        }
    }
    __syncthreads();
    for (int k = t; k < CHUNK; k += 256) {
        int i = base + k;
        if (i < ETOT) {
            int src, dst;
            if (i < EE) { src = ei[i]; dst = ei[EE + i]; }
            else { src = dst = i - EE; }
            int b = dst >> 8;
            int p = atomicAdd(&cur[b], 1);
            binned[sbase[b] + p] = make_uint2((unsigned)src, (unsigned)dst);
        }
    }
}

__global__ __launch_bounds__(256) void k_csr_final(const int* __restrict__ bucket_start,
                                                   const uint2* __restrict__ binned,
                                                   int* __restrict__ rowptr,
                                                   int* __restrict__ csrc) {
    __shared__ int hist[256];
    __shared__ int cur[256];
    __shared__ int wsum[4];
    int b = blockIdx.x;
    int t = threadIdx.x;
    int s0 = bucket_start[b], s1 = bucket_start[b + 1];
    int cnt = s1 - s0;
    hist[t] = 0;
    __syncthreads();
    for (int k = t; k < cnt; k += 256) {
        int dst = (int)binned[s0 + k].y;
        atomicAdd(&hist[dst & 255], 1);
    }
    __syncthreads();
    int v = hist[t];
    int lane = t & 63, w = t >> 6;
    int x = v;
    #pragma unroll
    for (int off = 1; off < 64; off <<= 1) {
        int y = __shfl_up(x, off);
        if (lane >= off) x += y;
    }
    if (lane == 63) wsum[w] = x;
    __syncthreads();
    int add = 0;
    #pragma unroll
    for (int k = 0; k < 4; k++) add += (k < w) ? wsum[k] : 0;
    int excl = x + add - v;
    int n = (b << 8) + t;
    if (n < NN) rowptr[n] = s0 + excl;
    if (b == 0 && t == 0) rowptr[NN] = ETOT;
    cur[t] = s0 + excl;
    __syncthreads();
    for (int k = t; k < cnt; k += 256) {
        uint2 pr = binned[s0 + k];
        int p = atomicAdd(&cur[pr.y & 255], 1);
        csrc[p] = (int)pr.x;
    }
}

// ---------------- GEMM h = x@W + per-node attention scores ----------------

template<int FIN>
__global__ __launch_bounds__(256) void k_gemm_scores(
        const float* __restrict__ x, const float* __restrict__ W,
        const float* __restrict__ a_src, const float* __restrict__ a_dst,
        float* __restrict__ h, float* __restrict__ ssrc, float* __restrict__ sdst) {
    __shared__ float wlds[FIN * HIDD];
    __shared__ float xlds[16 * FIN];
    int t = threadIdx.x;
    int nb = blockIdx.x * 16;
    for (int i = t; i < FIN * HIDD / 4; i += 256)
        ((float4*)wlds)[i] = ((const float4*)W)[i];
    for (int i = t; i < 16 * FIN / 4; i += 256)
        ((float4*)xlds)[i] = ((const float4*)(x + (size_t)nb * FIN))[i];
    __syncthreads();

    int nl = t >> 4;          // local node 0..15
    int q  = t & 15;          // j-quad 0..15
    int j0 = q * 4;
    float a0 = 0.f, a1 = 0.f, a2 = 0.f, a3 = 0.f;
    const float4* wl4 = (const float4*)wlds;
    const float4* xl4 = (const float4*)(xlds + nl * FIN);
    #pragma unroll
    for (int k4 = 0; k4 < FIN / 4; k4++) {
        float4 xv = xl4[k4];
        float4 wa = wl4[(k4 * 4 + 0) * 16 + q];
        float4 wb = wl4[(k4 * 4 + 1) * 16 + q];
        float4 wc = wl4[(k4 * 4 + 2) * 16 + q];
        float4 wd = wl4[(k4 * 4 + 3) * 16 + q];
        a0 += xv.x * wa.x + xv.y * wb.x + xv.z * wc.x + xv.w * wd.x;
        a1 += xv.x * wa.y + xv.y * wb.y + xv.z * wc.y + xv.w * wd.y;
        a2 += xv.x * wa.z + xv.y * wb.z + xv.z * wc.z + xv.w * wd.z;
        a3 += xv.x * wa.w + xv.y * wb.w + xv.z * wc.w + xv.w * wd.w;
    }
    int n = nb + nl;
    float4 hv = {a0, a1, a2, a3};
    *(float4*)(h + (size_t)n * HIDD + j0) = hv;

    float vs = a0 * a_src[j0] + a1 * a_src[j0 + 1] + a2 * a_src[j0 + 2] + a3 * a_src[j0 + 3];
    float vd = a0 * a_dst[j0] + a1 * a_dst[j0 + 1] + a2 * a_dst[j0 + 2] + a3 * a_dst[j0 + 3];
    vs += __shfl_xor(vs, 1); vs += __shfl_xor(vs, 2);
    vd += __shfl_xor(vd, 1); vd += __shfl_xor(vd, 2);
    if ((q & 3) == 0) {
        ssrc[n * NHEADS + (q >> 2)] = vs;
        sdst[n * NHEADS + (q >> 2)] = vd;
    }
}

// ---------------- per-destination aggregation (1 wave per node) ----------------

__global__ __launch_bounds__(64) void k_aggr(
        const float* __restrict__ h, const float* __restrict__ ssrc,
        const float* __restrict__ sdst, const int* __restrict__ rowptr,
        const int* __restrict__ csrc, const float* __restrict__ bias,
        float* __restrict__ out) {
    __shared__ float exl[64 * 4];
    __shared__ int srcl[64];
    int n = blockIdx.x;
    int lane = threadIdx.x;
    int hd = lane >> 4;
    int beg = rowptr[n], end = rowptr[n + 1];
    float4 sd = ((const float4*)sdst)[n];

    float z0 = 0.f, z1 = 0.f, z2 = 0.f, z3 = 0.f;
    for (int i = beg + lane; i < end; i += 64) {
        int s = csrc[i];
        float4 ss = ((const float4*)ssrc)[s];
        float e0 = ss.x + sd.x; e0 = e0 > 0.f ? e0 : 0.2f * e0; z0 += __expf(e0);
        float e1 = ss.y + sd.y; e1 = e1 > 0.f ? e1 : 0.2f * e1; z1 += __expf(e1);
        float e2 = ss.z + sd.z; e2 = e2 > 0.f ? e2 : 0.2f * e2; z2 += __expf(e2);
        float e3 = ss.w + sd.w; e3 = e3 > 0.f ? e3 : 0.2f * e3; z3 += __expf(e3);
    }
    for (int m = 1; m < 64; m <<= 1) {
        z0 += __shfl_xor(z0, m); z1 += __shfl_xor(z1, m);
        z2 += __shfl_xor(z2, m); z3 += __shfl_xor(z3, m);
    }
    float zh = (hd == 0) ? z0 : (hd == 1) ? z1 : (hd == 2) ? z2 : z3;
    float inv_z = 1.0f / (zh + 1e-16f);

    float acc = 0.f;
    for (int cb = beg; cb < end; cb += 64) {
        int m = min(64, end - cb);
        if (lane < m) {
            int s = csrc[cb + lane];
            srcl[lane] = s;
            float4 ss = ((const float4*)ssrc)[s];
            float e0 = ss.x + sd.x; e0 = e0 > 0.f ? e0 : 0.2f * e0;
            float e1 = ss.y + sd.y; e1 = e1 > 0.f ? e1 : 0.2f * e1;
            float e2 = ss.z + sd.z; e2 = e2 > 0.f ? e2 : 0.2f * e2;
            float e3 = ss.w + sd.w; e3 = e3 > 0.f ? e3 : 0.2f * e3;
            exl[lane * 4 + 0] = __expf(e0);
            exl[lane * 4 + 1] = __expf(e1);
            exl[lane * 4 + 2] = __expf(e2);
            exl[lane * 4 + 3] = __expf(e3);
        }
        __syncthreads();
        for (int j = 0; j < m; j++) {
            int s = srcl[j];
            acc += h[(size_t)s * HIDD + lane] * exl[j * 4 + hd];
        }
        __syncthreads();
    }
    float r = acc * inv_z + bias[lane];
    out[(size_t)n * HIDD + lane] = r > 0.f ? r : 0.f;
}

// ---------------- FC1: [N,64] @ [64,160] + b, ReLU ----------------
// 64-node tile; thread = (qg 0..7, ng 0..31): 2 nodes x 5 quads (40 acc).
// W quad reads are wave-broadcast (8 lanes same address); xT reads 2-way free.

__global__ __launch_bounds__(256) void k_fc1(const float* __restrict__ x,
        const float* __restrict__ W, const float* __restrict__ bias,
        float* __restrict__ out) {
    __shared__ float wl[64 * 160];      // 40 KB
    __shared__ float xt[64][66];        // transposed x-tile, padded
    int t = threadIdx.x;
    int nb = blockIdx.x * 64;
    for (int i = t; i < 64 * 160 / 4; i += 256)
        ((float4*)wl)[i] = ((const float4*)W)[i];
    #pragma unroll
    for (int r = 0; r < 4; r++) {
        int idx = t + r * 256;
        int node = idx & 63, kq = idx >> 6;       // kq 0..15
        int n = nb + node;
        float4 v = make_float4(0.f, 0.f, 0.f, 0.f);
        if (n < NN) v = *(const float4*)(x + (size_t)n * 64 + kq * 4);
        xt[kq * 4 + 0][node] = v.x;
        xt[kq * 4 + 1][node] = v.y;
        xt[kq * 4 + 2][node] = v.z;
        xt[kq * 4 + 3][node] = v.w;
    }
    __syncthreads();

    int qg = t & 7, ng = t >> 3;
    float acc[2][5][4] = {};
    const float4* wl4 = (const float4*)wl;        // 40 quads per row
    #pragma unroll 4
    for (int k = 0; k < 64; k++) {
        float2 xv = *(const float2*)&xt[k][ng * 2];
        #pragma unroll
        for (int i = 0; i < 5; i++) {
            float4 wv = wl4[k * 40 + qg + 8 * i];
            acc[0][i][0] += xv.x * wv.x; acc[0][i][1] += xv.x * wv.y;
            acc[0][i][2] += xv.x * wv.z; acc[0][i][3] += xv.x * wv.w;
            acc[1][i][0] += xv.y * wv.x; acc[1][i][1] += xv.y * wv.y;
            acc[1][i][2] += xv.y * wv.z; acc[1][i][3] += xv.y * wv.w;
        }
    }
    #pragma unroll
    for (int i = 0; i < 5; i++) {
        int j0 = (qg + 8 * i) * 4;
        float4 bv = *(const float4*)(bias + j0);
        #pragma unroll
        for (int r = 0; r < 2; r++) {
            int n = nb + ng * 2 + r;
            if (n < NN) {
                float4 o;
                o.x = acc[r][i][0] + bv.x; o.x = o.x > 0.f ? o.x : 0.f;
                o.y = acc[r][i][1] + bv.y; o.y = o.y > 0.f ? o.y : 0.f;
                o.z = acc[r][i][2] + bv.z; o.z = o.z > 0.f ? o.z : 0.f;
                o.w = acc[r][i][3] + bv.w; o.w = o.w > 0.f ? o.w : 0.f;
                *(float4*)(out + (size_t)n * 160 + j0) = o;
            }
        }
    }
}

// ---------------- FC2: [N,160] @ [160,64] + b ----------------
// 64-node tile; thread = (qg 0..15, ng 0..15): 4 nodes x 1 quad (16 acc).
// xT in LDS (43.5 KB -> 3 blocks/CU); W float4 from L1/L2 (40 KB, hot).

__global__ __launch_bounds__(256) void k_fc2(const float* __restrict__ x,
        const float* __restrict__ W, const float* __restrict__ bias,
        float* __restrict__ out) {
    __shared__ float xt[160][68];       // 43520 B
    int t = threadIdx.x;
    int nb = blockIdx.x * 64;
    #pragma unroll
    for (int r = 0; r < 10; r++) {
        int idx = t + r * 256;
        int node = idx & 63, kq = idx >> 6;       // kq 0..39
        int n = nb + node;
        float4 v = make_float4(0.f, 0.f, 0.f, 0.f);
        if (n < NN) v = *(const float4*)(x + (size_t)n * 160 + kq * 4);
        xt[kq * 4 + 0][node] = v.x;
        xt[kq * 4 + 1][node] = v.y;
        xt[kq * 4 + 2][node] = v.z;
        xt[kq * 4 + 3][node] = v.w;
    }
    __syncthreads();

    int qg = t & 15, ng = t >> 4;
    float acc[4][4] = {};
    const float4* Wg = (const float4*)W;          // 16 quads per row
    #pragma unroll 4
    for (int k = 0; k < 160; k++) {
        float4 wv = Wg[k * 16 + qg];
        float4 xv = *(const float4*)&xt[k][ng * 4];
        acc[0][0] += xv.x * wv.x; acc[0][1] += xv.x * wv.y;
        acc[0][2] += xv.x * wv.z; acc[0][3] += xv.x * wv.w;
        acc[1][0] += xv.y * wv.x; acc[1][1] += xv.y * wv.y;
        acc[1][2] += xv.y * wv.z; acc[1][3] += xv.y * wv.w;
        acc[2][0] += xv.z * wv.x; acc[2][1] += xv.z * wv.y;
        acc[2][2] += xv.z * wv.z; acc[2][3] += xv.z * wv.w;
        acc[3][0] += xv.w * wv.x; acc[3][1] += xv.w * wv.y;
        acc[3][2] += xv.w * wv.z; acc[3][3] += xv.w * wv.w;
    }
    int j0 = qg * 4;
    float4 bv = *(const float4*)(bias + j0);
    #pragma unroll
    for (int r = 0; r < 4; r++) {
        int n = nb + ng * 4 + r;
        if (n < NN) {
            float4 o;
            o.x = acc[r][0] + bv.x; o.y = acc[r][1] + bv.y;
            o.z = acc[r][2] + bv.z; o.w = acc[r][3] + bv.w;
            *(float4*)(out + (size_t)n * 64 + j0) = o;
        }
    }
}

// ---------------- launch ----------------

extern "C" void kernel_launch(void* const* d_in, const int* in_sizes, int n_in,
                              void* d_out, int out_size, void* d_ws, size_t ws_size,
                              hipStream_t stream) {
    const float* x   = (const float*)d_in[0];
    const int*   ei  = (const int*)d_in[1];
    const float* W0  = (const float*)d_in[2];
    const float* as0 = (const float*)d_in[3];
    const float* ad0 = (const float*)d_in[4];
    const float* b0  = (const float*)d_in[5];
    const float* W1  = (const float*)d_in[6];
    const float* as1 = (const float*)d_in[7];
    const float* ad1 = (const float*)d_in[8];
    const float* b1  = (const float*)d_in[9];
    const float* W2  = (const float*)d_in[10];
    const float* as2 = (const float*)d_in[11];
    const float* ad2 = (const float*)d_in[12];
    const float* b2  = (const float*)d_in[13];
    const float* fw1 = (const float*)d_in[14];
    const float* fb1 = (const float*)d_in[15];
    const float* fw2 = (const float*)d_in[16];
    const float* fb2 = (const float*)d_in[17];

    float* ws     = (float*)d_ws;
    float* h_buf  = ws;                          // N*64
    float* ssrc   = h_buf + (size_t)NN * HIDD;   // N*4
    float* sdst   = ssrc + (size_t)NN * NHEADS;  // N*4
    float* act    = sdst + (size_t)NN * NHEADS;  // N*64
    float* fcb    = act + (size_t)NN * HIDD;     // N*160 (FC scratch; binned aliases this)
    int*   rowptr = (int*)(fcb + (size_t)NN * FCD); // N+1
    int*   csrc   = rowptr + NN + 1;             // ETOT
    int*   bbase  = csrc + ETOT;                 // NEBLK*NBKT
    int*   bucket_count = bbase + NEBLK * NBKT;  // NBKT
    int*   bucket_start = bucket_count + NBKT;   // NBKT+1
    uint2* binned = (uint2*)fcb;                 // ETOT pairs (8B) <= N*160*4 bytes

    hipMemsetAsync(bucket_count, 0, NBKT * sizeof(int), stream);
    k_hist<<<NEBLK, 256, 0, stream>>>(ei, bucket_count, bbase);
    k_scanb<<<1, 256, 0, stream>>>(bucket_count, bucket_start);
    k_binwrite<<<NEBLK, 256, 0, stream>>>(ei, bucket_start, bbase, binned);
    k_csr_final<<<NBKT, 256, 0, stream>>>(bucket_start, binned, rowptr, csrc);

    // layer 0
    k_gemm_scores<128><<<NN / 16, 256, 0, stream>>>(x, W0, as0, ad0, h_buf, ssrc, sdst);
    k_aggr<<<NN, 64, 0, stream>>>(h_buf, ssrc, sdst, rowptr, csrc, b0, act);
    // layer 1
    k_gemm_scores<64><<<NN / 16, 256, 0, stream>>>(act, W1, as1, ad1, h_buf, ssrc, sdst);
    k_aggr<<<NN, 64, 0, stream>>>(h_buf, ssrc, sdst, rowptr, csrc, b1, act);
    // layer 2
    k_gemm_scores<64><<<NN / 16, 256, 0, stream>>>(act, W2, as2, ad2, h_buf, ssrc, sdst);
    k_aggr<<<NN, 64, 0, stream>>>(h_buf, ssrc, sdst, rowptr, csrc, b2, act);

    // FC head
    k_fc1<<<NFCB, 256, 0, stream>>>(act, fw1, fb1, fcb);
    k_fc2<<<NFCB, 256, 0, stream>>>(fcb, fw2, fb2, (float*)d_out);
}

// Round 5
// 266.719 us; speedup vs baseline: 1.6776x; 1.0732x over previous
//
#include <hip/hip_runtime.h>

#define NN 50000
#define EE 800000
#define ETOT (EE + NN)          // 850000
#define HIDD 64
#define NHEADS 4
#define FCD 160
#define OUTD 64

#define NBKT 196                // dst>>8 -> 196 buckets of 256 dst nodes
#define CHUNK 4096
#define NEBLK ((ETOT + CHUNK - 1) / CHUNK)   // 208
#define NFCB ((NN + 63) / 64)   // 782

// ---------------- CSR build: two-level bucketed counting sort ----------------
// No global atomics, no memset: per-chunk counts -> per-bucket scan -> bucket scan.

// pass 1: per-chunk LDS histogram of dst buckets -> bbase[bucket][chunk]
__global__ __launch_bounds__(256) void k_hist(const int* __restrict__ ei,
                                              int* __restrict__ bbase) {
    __shared__ int hist[NBKT];
    int t = threadIdx.x;
    for (int i = t; i < NBKT; i += 256) hist[i] = 0;
    __syncthreads();
    int base = blockIdx.x * CHUNK;
    for (int k = t; k < CHUNK; k += 256) {
        int i = base + k;
        if (i < ETOT) {
            int dst = (i < EE) ? ei[EE + i] : (i - EE);
            atomicAdd(&hist[dst >> 8], 1);
        }
    }
    __syncthreads();
    for (int b = t; b < NBKT; b += 256)
        bbase[b * NEBLK + blockIdx.x] = hist[b];
}

// pass 2a: per-bucket exclusive scan over its 208 chunk counts; emit totals
__global__ __launch_bounds__(256) void k_scanblk(int* __restrict__ bbase,
                                                 int* __restrict__ bucket_count) {
    int b = blockIdx.x, t = threadIdx.x;
    int v = (t < NEBLK) ? bbase[b * NEBLK + t] : 0;
    int lane = t & 63, w = t >> 6;
    int x = v;
    #pragma unroll
    for (int off = 1; off < 64; off <<= 1) {
        int y = __shfl_up(x, off);
        if (lane >= off) x += y;
    }
    __shared__ int wsum[4];
    if (lane == 63) wsum[w] = x;
    __syncthreads();
    int add = 0;
    #pragma unroll
    for (int k = 0; k < 4; k++) add += (k < w) ? wsum[k] : 0;
    int excl = x + add - v;
    if (t < NEBLK) bbase[b * NEBLK + t] = excl;
    if (t == NEBLK - 1) bucket_count[b] = excl + v;
}

// pass 2b: exclusive scan of the 196 bucket totals
__global__ __launch_bounds__(256) void k_scanb(const int* __restrict__ bucket_count,
                                               int* __restrict__ bucket_start) {
    int t = threadIdx.x;
    int v = (t < NBKT) ? bucket_count[t] : 0;
    int lane = t & 63, w = t >> 6;
    int x = v;
    #pragma unroll
    for (int off = 1; off < 64; off <<= 1) {
        int y = __shfl_up(x, off);
        if (lane >= off) x += y;
    }
    __shared__ int wsum[4];
    if (lane == 63) wsum[w] = x;
    __syncthreads();
    int add = 0;
    #pragma unroll
    for (int k = 0; k < 4; k++) add += (k < w) ? wsum[k] : 0;
    if (t < NBKT) bucket_start[t] = x + add - v;
    if (t == 0) bucket_start[NBKT] = ETOT;
}

// pass 3: write (src,dst) pairs grouped by bucket; per-block runs contiguous
__global__ __launch_bounds__(256) void k_binwrite(const int* __restrict__ ei,
                                                  const int* __restrict__ bucket_start,
                                                  const int* __restrict__ bbase,
                                                  uint2* __restrict__ binned) {
    __shared__ int hist[NBKT];
    __shared__ int sbase[NBKT];
    __shared__ int cur[NBKT];
    __shared__ int wsum[4];
    int t = threadIdx.x;
    for (int i = t; i < NBKT; i += 256) hist[i] = 0;
    __syncthreads();
    int base = blockIdx.x * CHUNK;
    for (int k = t; k < CHUNK; k += 256) {
        int i = base + k;
        if (i < ETOT) {
            int dst = (i < EE) ? ei[EE + i] : (i - EE);
            atomicAdd(&hist[dst >> 8], 1);
        }
    }
    __syncthreads();
    {
        int v = (t < NBKT) ? hist[t] : 0;
        int lane = t & 63, w = t >> 6;
        int x = v;
        #pragma unroll
        for (int off = 1; off < 64; off <<= 1) {
            int y = __shfl_up(x, off);
            if (lane >= off) x += y;
        }
        if (lane == 63) wsum[w] = x;
        __syncthreads();
        int add = 0;
        #pragma unroll
        for (int k = 0; k < 4; k++) add += (k < w) ? wsum[k] : 0;
        int excl = x + add - v;
        if (t < NBKT) {
            sbase[t] = bucket_start[t] + bbase[t * NEBLK + blockIdx.x] - excl;
            cur[t] = excl;
        }
    }
    __syncthreads();
    for (int k = t; k < CHUNK; k += 256) {
        int i = base + k;
        if (i < ETOT) {
            int src, dst;
            if (i < EE) { src = ei[i]; dst = ei[EE + i]; }
            else { src = dst = i - EE; }
            int b = dst >> 8;
            int p = atomicAdd(&cur[b], 1);
            binned[sbase[b] + p] = make_uint2((unsigned)src, (unsigned)dst);
        }
    }
}

// pass 4: one block per bucket -> rowptr + final csrc (bucket-local writes)
__global__ __launch_bounds__(256) void k_csr_final(const int* __restrict__ bucket_start,
                                                   const uint2* __restrict__ binned,
                                                   int* __restrict__ rowptr,
                                                   int* __restrict__ csrc) {
    __shared__ int hist[256];
    __shared__ int cur[256];
    __shared__ int wsum[4];
    int b = blockIdx.x;
    int t = threadIdx.x;
    int s0 = bucket_start[b], s1 = bucket_start[b + 1];
    int cnt = s1 - s0;
    hist[t] = 0;
    __syncthreads();
    for (int k = t; k < cnt; k += 256) {
        int dst = (int)binned[s0 + k].y;
        atomicAdd(&hist[dst & 255], 1);
    }
    __syncthreads();
    int v = hist[t];
    int lane = t & 63, w = t >> 6;
    int x = v;
    #pragma unroll
    for (int off = 1; off < 64; off <<= 1) {
        int y = __shfl_up(x, off);
        if (lane >= off) x += y;
    }
    if (lane == 63) wsum[w] = x;
    __syncthreads();
    int add = 0;
    #pragma unroll
    for (int k = 0; k < 4; k++) add += (k < w) ? wsum[k] : 0;
    int excl = x + add - v;
    int n = (b << 8) + t;
    if (n < NN) rowptr[n] = s0 + excl;
    if (b == 0 && t == 0) rowptr[NN] = ETOT;
    cur[t] = s0 + excl;
    __syncthreads();
    for (int k = t; k < cnt; k += 256) {
        uint2 pr = binned[s0 + k];
        int p = atomicAdd(&cur[pr.y & 255], 1);
        csrc[p] = (int)pr.x;
    }
}

// ---------------- GEMM h = x@W + per-node attention scores ----------------

template<int FIN>
__global__ __launch_bounds__(256) void k_gemm_scores(
        const float* __restrict__ x, const float* __restrict__ W,
        const float* __restrict__ a_src, const float* __restrict__ a_dst,
        float* __restrict__ h, float* __restrict__ ssrc, float* __restrict__ sdst) {
    __shared__ float wlds[FIN * HIDD];
    __shared__ float xlds[16 * FIN];
    int t = threadIdx.x;
    int nb = blockIdx.x * 16;
    for (int i = t; i < FIN * HIDD / 4; i += 256)
        ((float4*)wlds)[i] = ((const float4*)W)[i];
    for (int i = t; i < 16 * FIN / 4; i += 256)
        ((float4*)xlds)[i] = ((const float4*)(x + (size_t)nb * FIN))[i];
    __syncthreads();

    int nl = t >> 4;          // local node 0..15
    int q  = t & 15;          // j-quad 0..15
    int j0 = q * 4;
    float a0 = 0.f, a1 = 0.f, a2 = 0.f, a3 = 0.f;
    const float4* wl4 = (const float4*)wlds;
    const float4* xl4 = (const float4*)(xlds + nl * FIN);
    #pragma unroll
    for (int k4 = 0; k4 < FIN / 4; k4++) {
        float4 xv = xl4[k4];
        float4 wa = wl4[(k4 * 4 + 0) * 16 + q];
        float4 wb = wl4[(k4 * 4 + 1) * 16 + q];
        float4 wc = wl4[(k4 * 4 + 2) * 16 + q];
        float4 wd = wl4[(k4 * 4 + 3) * 16 + q];
        a0 += xv.x * wa.x + xv.y * wb.x + xv.z * wc.x + xv.w * wd.x;
        a1 += xv.x * wa.y + xv.y * wb.y + xv.z * wc.y + xv.w * wd.y;
        a2 += xv.x * wa.z + xv.y * wb.z + xv.z * wc.z + xv.w * wd.z;
        a3 += xv.x * wa.w + xv.y * wb.w + xv.z * wc.w + xv.w * wd.w;
    }
    int n = nb + nl;
    float4 hv = {a0, a1, a2, a3};
    *(float4*)(h + (size_t)n * HIDD + j0) = hv;

    float vs = a0 * a_src[j0] + a1 * a_src[j0 + 1] + a2 * a_src[j0 + 2] + a3 * a_src[j0 + 3];
    float vd = a0 * a_dst[j0] + a1 * a_dst[j0 + 1] + a2 * a_dst[j0 + 2] + a3 * a_dst[j0 + 3];
    vs += __shfl_xor(vs, 1); vs += __shfl_xor(vs, 2);
    vd += __shfl_xor(vd, 1); vd += __shfl_xor(vd, 2);
    if ((q & 3) == 0) {
        ssrc[n * NHEADS + (q >> 2)] = vs;
        sdst[n * NHEADS + (q >> 2)] = vd;
    }
}

// ---------------- per-destination aggregation: SINGLE fused sweep ----------------
// out = (sum_i w_i * h[s_i]) / (sum_i w_i); w_i = exp(leakyrelu(ssrc+sdst)).
// Staging lane accumulates its edges' w into per-lane z; one reduce at the end.

__global__ __launch_bounds__(64) void k_aggr(
        const float* __restrict__ h, const float* __restrict__ ssrc,
        const float* __restrict__ sdst, const int* __restrict__ rowptr,
        const int* __restrict__ csrc, const float* __restrict__ bias,
        float* __restrict__ out) {
    __shared__ float exl[64 * 4];
    __shared__ int srcl[64];
    int n = blockIdx.x;
    int lane = threadIdx.x;
    int hd = lane >> 4;
    int beg = rowptr[n], end = rowptr[n + 1];
    float4 sd = ((const float4*)sdst)[n];

    float acc = 0.f;
    float z0 = 0.f, z1 = 0.f, z2 = 0.f, z3 = 0.f;
    for (int cb = beg; cb < end; cb += 64) {
        int m = min(64, end - cb);
        if (lane < m) {
            int s = csrc[cb + lane];
            srcl[lane] = s;
            float4 ss = ((const float4*)ssrc)[s];
            float e0 = ss.x + sd.x; e0 = e0 > 0.f ? e0 : 0.2f * e0;
            float e1 = ss.y + sd.y; e1 = e1 > 0.f ? e1 : 0.2f * e1;
            float e2 = ss.z + sd.z; e2 = e2 > 0.f ? e2 : 0.2f * e2;
            float e3 = ss.w + sd.w; e3 = e3 > 0.f ? e3 : 0.2f * e3;
            float w0 = __expf(e0), w1 = __expf(e1), w2 = __expf(e2), w3 = __expf(e3);
            z0 += w0; z1 += w1; z2 += w2; z3 += w3;
            exl[lane * 4 + 0] = w0;
            exl[lane * 4 + 1] = w1;
            exl[lane * 4 + 2] = w2;
            exl[lane * 4 + 3] = w3;
        }
        __syncthreads();
        for (int j = 0; j < m; j++) {
            int s = srcl[j];
            acc += h[(size_t)s * HIDD + lane] * exl[j * 4 + hd];
        }
        __syncthreads();
    }
    #pragma unroll
    for (int m = 1; m < 64; m <<= 1) {
        z0 += __shfl_xor(z0, m); z1 += __shfl_xor(z1, m);
        z2 += __shfl_xor(z2, m); z3 += __shfl_xor(z3, m);
    }
    float zh = (hd == 0) ? z0 : (hd == 1) ? z1 : (hd == 2) ? z2 : z3;
    float r = acc / (zh + 1e-16f) + bias[lane];
    out[(size_t)n * HIDD + lane] = r > 0.f ? r : 0.f;
}

// ---------------- FC1: [N,64] @ [64,160] + b, ReLU ----------------

__global__ __launch_bounds__(256) void k_fc1(const float* __restrict__ x,
        const float* __restrict__ W, const float* __restrict__ bias,
        float* __restrict__ out) {
    __shared__ float wl[64 * 160];      // 40 KB
    __shared__ float xt[64][66];        // transposed x-tile, padded
    int t = threadIdx.x;
    int nb = blockIdx.x * 64;
    for (int i = t; i < 64 * 160 / 4; i += 256)
        ((float4*)wl)[i] = ((const float4*)W)[i];
    #pragma unroll
    for (int r = 0; r < 4; r++) {
        int idx = t + r * 256;
        int node = idx & 63, kq = idx >> 6;       // kq 0..15
        int n = nb + node;
        float4 v = make_float4(0.f, 0.f, 0.f, 0.f);
        if (n < NN) v = *(const float4*)(x + (size_t)n * 64 + kq * 4);
        xt[kq * 4 + 0][node] = v.x;
        xt[kq * 4 + 1][node] = v.y;
        xt[kq * 4 + 2][node] = v.z;
        xt[kq * 4 + 3][node] = v.w;
    }
    __syncthreads();

    int qg = t & 7, ng = t >> 3;
    float acc[2][5][4] = {};
    const float4* wl4 = (const float4*)wl;        // 40 quads per row
    #pragma unroll 4
    for (int k = 0; k < 64; k++) {
        float2 xv = *(const float2*)&xt[k][ng * 2];
        #pragma unroll
        for (int i = 0; i < 5; i++) {
            float4 wv = wl4[k * 40 + qg + 8 * i];
            acc[0][i][0] += xv.x * wv.x; acc[0][i][1] += xv.x * wv.y;
            acc[0][i][2] += xv.x * wv.z; acc[0][i][3] += xv.x * wv.w;
            acc[1][i][0] += xv.y * wv.x; acc[1][i][1] += xv.y * wv.y;
            acc[1][i][2] += xv.y * wv.z; acc[1][i][3] += xv.y * wv.w;
        }
    }
    #pragma unroll
    for (int i = 0; i < 5; i++) {
        int j0 = (qg + 8 * i) * 4;
        float4 bv = *(const float4*)(bias + j0);
        #pragma unroll
        for (int r = 0; r < 2; r++) {
            int n = nb + ng * 2 + r;
            if (n < NN) {
                float4 o;
                o.x = acc[r][i][0] + bv.x; o.x = o.x > 0.f ? o.x : 0.f;
                o.y = acc[r][i][1] + bv.y; o.y = o.y > 0.f ? o.y : 0.f;
                o.z = acc[r][i][2] + bv.z; o.z = o.z > 0.f ? o.z : 0.f;
                o.w = acc[r][i][3] + bv.w; o.w = o.w > 0.f ? o.w : 0.f;
                *(float4*)(out + (size_t)n * 160 + j0) = o;
            }
        }
    }
}

// ---------------- FC2: [N,160] @ [160,64] + b ----------------

__global__ __launch_bounds__(256) void k_fc2(const float* __restrict__ x,
        const float* __restrict__ W, const float* __restrict__ bias,
        float* __restrict__ out) {
    __shared__ float xt[160][68];       // 43520 B
    int t = threadIdx.x;
    int nb = blockIdx.x * 64;
    #pragma unroll
    for (int r = 0; r < 10; r++) {
        int idx = t + r * 256;
        int node = idx & 63, kq = idx >> 6;       // kq 0..39
        int n = nb + node;
        float4 v = make_float4(0.f, 0.f, 0.f, 0.f);
        if (n < NN) v = *(const float4*)(x + (size_t)n * 160 + kq * 4);
        xt[kq * 4 + 0][node] = v.x;
        xt[kq * 4 + 1][node] = v.y;
        xt[kq * 4 + 2][node] = v.z;
        xt[kq * 4 + 3][node] = v.w;
    }
    __syncthreads();

    int qg = t & 15, ng = t >> 4;
    float acc[4][4] = {};
    const float4* Wg = (const float4*)W;          // 16 quads per row
    #pragma unroll 4
    for (int k = 0; k < 160; k++) {
        float4 wv = Wg[k * 16 + qg];
        float4 xv = *(const float4*)&xt[k][ng * 4];
        acc[0][0] += xv.x * wv.x; acc[0][1] += xv.x * wv.y;
        acc[0][2] += xv.x * wv.z; acc[0][3] += xv.x * wv.w;
        acc[1][0] += xv.y * wv.x; acc[1][1] += xv.y * wv.y;
        acc[1][2] += xv.y * wv.z; acc[1][3] += xv.y * wv.w;
        acc[2][0] += xv.z * wv.x; acc[2][1] += xv.z * wv.y;
        acc[2][2] += xv.z * wv.z; acc[2][3] += xv.z * wv.w;
        acc[3][0] += xv.w * wv.x; acc[3][1] += xv.w * wv.y;
        acc[3][2] += xv.w * wv.z; acc[3][3] += xv.w * wv.w;
    }
    int j0 = qg * 4;
    float4 bv = *(const float4*)(bias + j0);
    #pragma unroll
    for (int r = 0; r < 4; r++) {
        int n = nb + ng * 4 + r;
        if (n < NN) {
            float4 o;
            o.x = acc[r][0] + bv.x; o.y = acc[r][1] + bv.y;
            o.z = acc[r][2] + bv.z; o.w = acc[r][3] + bv.w;
            *(float4*)(out + (size_t)n * 64 + j0) = o;
        }
    }
}

// ---------------- launch ----------------

extern "C" void kernel_launch(void* const* d_in, const int* in_sizes, int n_in,
                              void* d_out, int out_size, void* d_ws, size_t ws_size,
                              hipStream_t stream) {
    const float* x   = (const float*)d_in[0];
    const int*   ei  = (const int*)d_in[1];
    const float* W0  = (const float*)d_in[2];
    const float* as0 = (const float*)d_in[3];
    const float* ad0 = (const float*)d_in[4];
    const float* b0  = (const float*)d_in[5];
    const float* W1  = (const float*)d_in[6];
    const float* as1 = (const float*)d_in[7];
    const float* ad1 = (const float*)d_in[8];
    const float* b1  = (const float*)d_in[9];
    const float* W2  = (const float*)d_in[10];
    const float* as2 = (const float*)d_in[11];
    const float* ad2 = (const float*)d_in[12];
    const float* b2  = (const float*)d_in[13];
    const float* fw1 = (const float*)d_in[14];
    const float* fb1 = (const float*)d_in[15];
    const float* fw2 = (const float*)d_in[16];
    const float* fb2 = (const float*)d_in[17];

    float* ws     = (float*)d_ws;
    float* h_buf  = ws;                          // N*64
    float* ssrc   = h_buf + (size_t)NN * HIDD;   // N*4
    float* sdst   = ssrc + (size_t)NN * NHEADS;  // N*4
    float* act    = sdst + (size_t)NN * NHEADS;  // N*64
    float* fcb    = act + (size_t)NN * HIDD;     // N*160 (FC scratch; binned aliases this)
    int*   rowptr = (int*)(fcb + (size_t)NN * FCD); // N+1
    int*   csrc   = rowptr + NN + 1;             // ETOT
    int*   bbase  = csrc + ETOT;                 // NBKT*NEBLK
    int*   bucket_count = bbase + NBKT * NEBLK;  // NBKT
    int*   bucket_start = bucket_count + NBKT;   // NBKT+1
    uint2* binned = (uint2*)fcb;                 // ETOT pairs (8B) <= N*160*4 bytes

    k_hist<<<NEBLK, 256, 0, stream>>>(ei, bbase);
    k_scanblk<<<NBKT, 256, 0, stream>>>(bbase, bucket_count);
    k_scanb<<<1, 256, 0, stream>>>(bucket_count, bucket_start);
    k_binwrite<<<NEBLK, 256, 0, stream>>>(ei, bucket_start, bbase, binned);
    k_csr_final<<<NBKT, 256, 0, stream>>>(bucket_start, binned, rowptr, csrc);

    // layer 0
    k_gemm_scores<128><<<NN / 16, 256, 0, stream>>>(x, W0, as0, ad0, h_buf, ssrc, sdst);
    k_aggr<<<NN, 64, 0, stream>>>(h_buf, ssrc, sdst, rowptr, csrc, b0, act);
    // layer 1
    k_gemm_scores<64><<<NN / 16, 256, 0, stream>>>(act, W1, as1, ad1, h_buf, ssrc, sdst);
    k_aggr<<<NN, 64, 0, stream>>>(h_buf, ssrc, sdst, rowptr, csrc, b1, act);
    // layer 2
    k_gemm_scores<64><<<NN / 16, 256, 0, stream>>>(act, W2, as2, ad2, h_buf, ssrc, sdst);
    k_aggr<<<NN, 64, 0, stream>>>(h_buf, ssrc, sdst, rowptr, csrc, b2, act);

    // FC head
    k_fc1<<<NFCB, 256, 0, stream>>>(act, fw1, fb1, fcb);
    k_fc2<<<NFCB, 256, 0, stream>>>(fcb, fw2, fb2, (float*)d_out);
}